// Round 1
// baseline (25.133 us; speedup 1.0000x reference)
//
#include <hip/hip_runtime.h>
#include <math.h>

// AttController: two cascaded PIDs (angle -> rate) + inertia coupling.
// Inputs (setup_inputs order), all float32:
//   0: ref_rpy      (N,3)
//   1: meas_rpy     (N,3)
//   2: meas_omegab  (N,3)
//   3: J            (N,3,3)
//   4: integ        (6,N)   rows 0..2 angle, 3..5 rate
//   5: prev_err     (6,N)
//   6: d_filt       (6,N)
// Output: tau (N,3) float32.

#define PI_F 3.14159265358979323846f
#define TWO_PI_F 6.28318530717958647692f

__global__ __launch_bounds__(256) void att_ctrl_kernel(
    const float* __restrict__ ref_rpy,
    const float* __restrict__ meas_rpy,
    const float* __restrict__ meas_omegab,
    const float* __restrict__ J,
    const float* __restrict__ integ,
    const float* __restrict__ prev_err,
    const float* __restrict__ d_filt,
    float* __restrict__ out,
    int n)
{
    int i = blockIdx.x * blockDim.x + threadIdx.x;
    if (i >= n) return;

    // ---- constants (angle PID: tau=0 -> alpha=1; kd=0 -> D-term drops) ----
    const float DT_A = 0.01f;                       // 1/100
    const float ANG_KP[3] = {6.0f, 6.0f, 3.0f};
    const float ANG_KI[3] = {1.0f, 1.0f, 0.5f};
    const float ANG_LIM[3] = {10.0f, 10.0f, 5.0f};

    const float DT_R = 0.002f;                      // 1/500
    const float RATE_KP[3] = {0.25f, 0.25f, 0.12f};
    const float RATE_KI[3] = {0.5f, 0.5f, 0.1f};
    const float RATE_KD[3] = {0.0025f, 0.0025f, 0.0f};
    const float RATE_TAU   = 0.005f;
    const float ALPHA_R    = DT_R / (RATE_TAU + DT_R);   // 2/7 in f32
    const float RATE_LIM[3] = {1.0f, 1.0f, 0.5f};

    // ---- load per-body vectors (12B/lane, coalesced across wave) ----
    const float* rr = ref_rpy   + 3 * (size_t)i;
    const float* mr = meas_rpy  + 3 * (size_t)i;
    const float* mw = meas_omegab + 3 * (size_t)i;

    float err[3];
    err[0] = rr[0] - mr[0];
    err[1] = rr[1] - mr[1];
    err[2] = rr[2] - mr[2];
    // wrap yaw into [-pi, pi] (single wrap, matching reference where-chain)
    if (err[2] >  PI_F) err[2] -= TWO_PI_F;
    if (err[2] < -PI_F) err[2] += TWO_PI_F;

    float w[3] = {mw[0], mw[1], mw[2]};

    // ---- angle PID -> omega_ref ----
    float omega_ref[3];
    #pragma unroll
    for (int k = 0; k < 3; ++k) {
        float integ_n = integ[(size_t)k * n + i] + err[k] * DT_A;
        // kd == 0 for all angle axes -> derivative term contributes nothing
        float u = ANG_KP[k] * err[k] + ANG_KI[k] * integ_n;
        u = fminf(fmaxf(u, -ANG_LIM[k]), ANG_LIM[k]);
        omega_ref[k] = u;
    }

    // ---- rate PID -> alpha_ref ----
    float alpha_ref[3];
    #pragma unroll
    for (int k = 0; k < 3; ++k) {
        float e = omega_ref[k] - w[k];
        float integ_n = integ[(size_t)(k + 3) * n + i] + e * DT_R;
        float d_raw = (e - prev_err[(size_t)(k + 3) * n + i]) / DT_R;
        float df = d_filt[(size_t)(k + 3) * n + i];
        float d_n = df + ALPHA_R * (d_raw - df);
        float u = RATE_KP[k] * e + RATE_KI[k] * integ_n + RATE_KD[k] * d_n;
        u = fminf(fmaxf(u, -RATE_LIM[k]), RATE_LIM[k]);
        alpha_ref[k] = u;
    }

    // ---- inertia coupling: tau = J*alpha_ref + w x (J*w) ----
    const float* Ji = J + 9 * (size_t)i;
    float Jw[3], Ja[3];
    #pragma unroll
    for (int r = 0; r < 3; ++r) {
        Jw[r] = Ji[3*r+0] * w[0] + Ji[3*r+1] * w[1] + Ji[3*r+2] * w[2];
        Ja[r] = Ji[3*r+0] * alpha_ref[0] + Ji[3*r+1] * alpha_ref[1] + Ji[3*r+2] * alpha_ref[2];
    }
    float cx = w[1] * Jw[2] - w[2] * Jw[1];
    float cy = w[2] * Jw[0] - w[0] * Jw[2];
    float cz = w[0] * Jw[1] - w[1] * Jw[0];

    float* o = out + 3 * (size_t)i;
    o[0] = Ja[0] + cx;
    o[1] = Ja[1] + cy;
    o[2] = Ja[2] + cz;
}

extern "C" void kernel_launch(void* const* d_in, const int* in_sizes, int n_in,
                              void* d_out, int out_size, void* d_ws, size_t ws_size,
                              hipStream_t stream) {
    const float* ref_rpy     = (const float*)d_in[0];
    const float* meas_rpy    = (const float*)d_in[1];
    const float* meas_omegab = (const float*)d_in[2];
    const float* J           = (const float*)d_in[3];
    const float* integ       = (const float*)d_in[4];
    const float* prev_err    = (const float*)d_in[5];
    const float* d_filt      = (const float*)d_in[6];
    float* out = (float*)d_out;

    int n = in_sizes[0] / 3;   // ref_rpy is (N,3)
    int block = 256;
    int grid = (n + block - 1) / block;
    att_ctrl_kernel<<<grid, block, 0, stream>>>(
        ref_rpy, meas_rpy, meas_omegab, J, integ, prev_err, d_filt, out, n);
}